// Round 1
// baseline (425.130 us; speedup 1.0000x reference)
//
#include <hip/hip_runtime.h>
#include <stdint.h>
#include <stddef.h>

typedef unsigned short u16;
typedef short bf16x8 __attribute__((ext_vector_type(8)));
typedef float f32x4 __attribute__((ext_vector_type(4)));

#define LR 2048
#define LOG2E 1.44269504088896f

__device__ __forceinline__ u16 f2bf(float f) {
  unsigned u = __float_as_uint(f);
  unsigned r = u + 0x7fffu + ((u >> 16) & 1u);
  return (u16)(r >> 16);
}

__device__ __forceinline__ void gl_lds16(const void* g, void* l) {
  __builtin_amdgcn_global_load_lds((__attribute__((address_space(1))) void*)g,
                                   (__attribute__((address_space(3))) void*)l,
                                   16, 0, 0);
}

// ---------------- Hilbert permutation (closed form, no sort) ----------------
// perm[segpos+t] = row-major cell index of the t-th cell (by Hilbert distance)
// among the first L cells of the n x n grid. L = n*n  -> d2xy(t).
// L = n*n/2 (bottom half): quadrants (0,0) [d in 0..L/2) and (1,0)
// [d in 3L/2..2L) -> d2xy(t < L/2 ? t : t + L).
__global__ void hilbert_kernel(int* __restrict__ perm) {
  int idx = blockIdx.x * 256 + threadIdx.x;
  if (idx >= 14336) return;
  int seg = (idx < 2048) ? 0 : (idx < 6144 ? 1 : 2);
  int segpos = (seg == 0) ? 0 : (seg == 1 ? 2048 : 6144);
  int L = 2048 << seg;
  int n = (seg == 2) ? 128 : 64;
  int t = idx - segpos;
  int d = (L == n * n) ? t : ((t < (L >> 1)) ? t : t + L);
  int x = 0, y = 0;
  for (int s = 1; s < n; s <<= 1) {
    int rx = 1 & (d >> 1);
    int ry = 1 & (d ^ rx);
    if (ry == 0) {
      if (rx == 1) { x = s - 1 - x; y = s - 1 - y; }
      int tmp = x; x = y; y = tmp;
    }
    x += s * rx; y += s * ry;
    d >>= 2;
  }
  perm[idx] = y * n + x;
}

// ---------------- weight transpose + convert: [K][N] f32 -> [N][K] bf16 ------
__global__ void wtrans_kernel(const float* __restrict__ s0, const float* __restrict__ s1,
                              const float* __restrict__ s2, u16* __restrict__ dst,
                              int K, int N) {
  const float* S = (blockIdx.z == 0) ? s0 : (blockIdx.z == 1 ? s1 : s2);
  u16* D = dst + (size_t)blockIdx.z * K * N;
  __shared__ float tl[32][33];
  int n0 = blockIdx.x * 32, k0 = blockIdx.y * 32;
  int tx = threadIdx.x, ty = threadIdx.y;  // (32,8)
  #pragma unroll
  for (int i = 0; i < 4; i++)
    tl[ty + 8 * i][tx] = S[(size_t)(k0 + ty + 8 * i) * N + n0 + tx];
  __syncthreads();
  #pragma unroll
  for (int i = 0; i < 4; i++)
    D[(size_t)(n0 + ty + 8 * i) * K + k0 + tx] = f2bf(tl[tx][ty + 8 * i]);
}

// ---------------- gather x rows: hilbert perm + dilation reorder, f32->bf16 --
// storage row rr (segment-local rl): t = (rl%2048)*rate + rl/2048 (hilbert idx)
// xh[rr] = x[segpos + perm[segpos + t]]
__global__ void gather_kernel(const float* __restrict__ x, const int* __restrict__ perm,
                              u16* __restrict__ xh) {
  int rr = blockIdx.x;
  int seg = (rr < 2048) ? 0 : (rr < 6144 ? 1 : 2);
  int segpos = (seg == 0) ? 0 : (seg == 1 ? 2048 : 6144);
  int rate = 1 << seg;
  int rl = rr - segpos;
  int t = (rl & (LR - 1)) * rate + (rl >> 11);
  int orig = segpos + perm[segpos + t];
  float4 v = *((const float4*)(x + (size_t)orig * 1024) + threadIdx.x);
  ushort4 o;
  o.x = f2bf(v.x); o.y = f2bf(v.y); o.z = f2bf(v.z); o.w = f2bf(v.w);
  *((ushort4*)(xh + (size_t)rr * 1024) + threadIdx.x) = o;
}

// ---------------- QKV GEMM: [14336,1024] x per-seg W^T[3072,1024] -> bf16 ----
__global__ __launch_bounds__(256) void qkv_gemm_kernel(
    const u16* __restrict__ A, const u16* __restrict__ Bt,
    const float* __restrict__ b0, const float* __restrict__ b1,
    const float* __restrict__ b2, u16* __restrict__ C) {
  __shared__ char smem[35328];
  char* As = smem;           // [128][64] bf16, swizzled
  char* Bs = smem + 16384;
  const int tid = threadIdx.x;
  const int lane = tid & 63, wid = tid >> 6;
  const int wm = wid >> 1, wn = wid & 1;
  const int rb = blockIdx.x, nb = blockIdx.y;
  const int seg = (rb < 16) ? 0 : (rb < 48 ? 1 : 2);
  const float* bias = (seg == 0) ? b0 : (seg == 1 ? b1 : b2);
  const size_t arow0 = (size_t)rb * 128;
  const char* Ab = (const char*)(A + arow0 * 1024);
  const char* Bb = (const char*)(Bt + ((size_t)seg * 3072 + (size_t)nb * 128) * 1024);

  f32x4 acc[4][4] = {};

  for (int kt = 0; kt < 16; kt++) {
    #pragma unroll
    for (int it = 0; it < 4; it++) {
      int p = (it * 256 + tid) * 16;
      int e = p ^ (((p >> 7) & 7) << 4);
      int row = e >> 7, col = e & 127;
      gl_lds16(Ab + (size_t)row * 2048 + kt * 128 + col, As + it * 4096 + wid * 1024);
      gl_lds16(Bb + (size_t)row * 2048 + kt * 128 + col, Bs + it * 4096 + wid * 1024);
    }
    __syncthreads();
    #pragma unroll
    for (int kc = 0; kc < 2; kc++) {
      bf16x8 af[4], bfr[4];
      #pragma unroll
      for (int m = 0; m < 4; m++) {
        int row = wm * 64 + m * 16 + (lane & 15);
        int e = row * 128 + kc * 64 + ((lane >> 4) << 4);
        af[m] = *(const bf16x8*)(As + (e ^ ((row & 7) << 4)));
      }
      #pragma unroll
      for (int n = 0; n < 4; n++) {
        int row = wn * 64 + n * 16 + (lane & 15);
        int e = row * 128 + kc * 64 + ((lane >> 4) << 4);
        bfr[n] = *(const bf16x8*)(Bs + (e ^ ((row & 7) << 4)));
      }
      #pragma unroll
      for (int m = 0; m < 4; m++)
        #pragma unroll
        for (int n = 0; n < 4; n++)
          acc[m][n] = __builtin_amdgcn_mfma_f32_16x16x32_bf16(af[m], bfr[n], acc[m][n], 0, 0, 0);
    }
    __syncthreads();
  }
  // epilogue: bias + bf16, LDS bounce (stride 272B) for coalesced stores
  float bv[4];
  #pragma unroll
  for (int n = 0; n < 4; n++) bv[n] = bias[nb * 128 + wn * 64 + n * 16 + (lane & 15)];
  #pragma unroll
  for (int m = 0; m < 4; m++)
    #pragma unroll
    for (int n = 0; n < 4; n++)
      #pragma unroll
      for (int j = 0; j < 4; j++) {
        int r = wm * 64 + m * 16 + ((lane >> 4) << 2) + j;
        int c = wn * 64 + n * 16 + (lane & 15);
        *(u16*)(smem + r * 272 + c * 2) = f2bf(acc[m][n][j] + bv[n]);
      }
  __syncthreads();
  #pragma unroll
  for (int it = 0; it < 8; it++) {
    int ci = it * 256 + tid;
    int row = ci >> 4, c16 = ci & 15;
    bf16x8 vv = *(const bf16x8*)(smem + row * 272 + c16 * 16);
    u16* crow = C + (arow0 + row) * 3072 + nb * 128;
    *(bf16x8*)((char*)crow + c16 * 16) = vv;
  }
}

// ---------------- flash attention over dilated (contiguous-storage) rows -----
__global__ __launch_bounds__(256) void attn_kernel(const u16* __restrict__ qkv,
                                                   u16* __restrict__ opre) {
  __shared__ char smem[32768];
  char* Qs = smem;          // [64 q][64 d] bf16 swizzled
  char* Ks = smem + 8192;   // [64 key][64 d]
  char* Vt = smem + 16384;  // [64 d][64 key]
  const int tid = threadIdx.x;
  const int lane = tid & 63;
  const int wid = tid >> 6;
  char* Psw = smem + 24576 + wid * 2048;  // per-wave [16 q][64 key]
  const int by = blockIdx.y;
  const int seg = by >> 4, h = by & 15;
  const int segrow = (seg == 0) ? 0 : (seg == 1 ? 2048 : 6144);
  const int rate = 1 << seg;
  const int off = h & (rate - 1);
  const int base = segrow + off * LR;   // head's contiguous 2048 rows
  const int q0 = blockIdx.x * 64;
  const char* qb = (const char*)qkv;

  #pragma unroll
  for (int it = 0; it < 2; it++) {
    int p = (it * 256 + tid) * 16;
    int e = p ^ (((p >> 7) & 7) << 4);
    int row = e >> 7, col = e & 127;
    gl_lds16(qb + (size_t)(base + q0 + row) * 6144 + h * 128 + col,
             Qs + it * 4096 + wid * 1024);
  }

  float Mrun[4] = {-INFINITY, -INFINITY, -INFINITY, -INFINITY};
  float Lrun[4] = {0.f, 0.f, 0.f, 0.f};
  f32x4 accO[4] = {};
  const int kb_ = tid >> 4;
  const int db_ = tid & 15;

  for (int kt = 0; kt < 32; kt++) {
    #pragma unroll
    for (int it = 0; it < 2; it++) {
      int p = (it * 256 + tid) * 16;
      int e = p ^ (((p >> 7) & 7) << 4);
      int row = e >> 7, col = e & 127;
      gl_lds16(qb + (size_t)(base + kt * 64 + row) * 6144 + 2048 + h * 128 + col,
               Ks + it * 4096 + wid * 1024);
    }
    {  // V tile, transposed in-register into Vt[d][key]
      ushort4 vv[4];
      #pragma unroll
      for (int kk = 0; kk < 4; kk++)
        vv[kk] = *(const ushort4*)(qb + (size_t)(base + kt * 64 + kb_ * 4 + kk) * 6144 +
                                   4096 + h * 128 + db_ * 8);
      const u16* vp = (const u16*)vv;
      #pragma unroll
      for (int dd = 0; dd < 4; dd++) {
        int d = db_ * 4 + dd;
        ushort4 w4;
        w4.x = vp[0 + dd]; w4.y = vp[4 + dd]; w4.z = vp[8 + dd]; w4.w = vp[12 + dd];
        int addr = d * 128 + kb_ * 8;
        *(ushort4*)(Vt + (addr ^ ((d & 7) << 4))) = w4;
      }
    }
    __syncthreads();

    f32x4 sacc[4] = {};
    #pragma unroll
    for (int kc = 0; kc < 2; kc++) {
      bf16x8 qf;
      {
        int qrow = wid * 16 + (lane & 15);
        int e = qrow * 128 + kc * 64 + ((lane >> 4) << 4);
        qf = *(const bf16x8*)(Qs + (e ^ ((qrow & 7) << 4)));
      }
      #pragma unroll
      for (int n = 0; n < 4; n++) {
        int krow = n * 16 + (lane & 15);
        int e = krow * 128 + kc * 64 + ((lane >> 4) << 4);
        bf16x8 kf = *(const bf16x8*)(Ks + (e ^ ((krow & 7) << 4)));
        sacc[n] = __builtin_amdgcn_mfma_f32_16x16x32_bf16(qf, kf, sacc[n], 0, 0, 0);
      }
    }

    float pb[4][4];
    #pragma unroll
    for (int j = 0; j < 4; j++) {
      float m = fmaxf(fmaxf(sacc[0][j], sacc[1][j]), fmaxf(sacc[2][j], sacc[3][j])) * 0.125f;
      #pragma unroll
      for (int msk = 1; msk < 16; msk <<= 1) m = fmaxf(m, __shfl_xor(m, msk, 16));
      float mnew = fmaxf(Mrun[j], m);
      float rf = exp2f((Mrun[j] - mnew) * LOG2E);
      float ssum = 0.f;
      #pragma unroll
      for (int n = 0; n < 4; n++) {
        float pv = exp2f((sacc[n][j] * 0.125f - mnew) * LOG2E);
        pb[n][j] = pv; ssum += pv;
      }
      #pragma unroll
      for (int msk = 1; msk < 16; msk <<= 1) ssum += __shfl_xor(ssum, msk, 16);
      Lrun[j] = Lrun[j] * rf + ssum;
      Mrun[j] = mnew;
      #pragma unroll
      for (int db = 0; db < 4; db++) accO[db][j] *= rf;
    }
    #pragma unroll
    for (int n = 0; n < 4; n++)
      #pragma unroll
      for (int j = 0; j < 4; j++) {
        int q = ((lane >> 4) << 2) + j;
        int addr = q * 128 + (n * 16 + (lane & 15)) * 2;
        *(u16*)(Psw + (addr ^ ((q & 7) << 4))) = f2bf(pb[n][j]);
      }
    #pragma unroll
    for (int c = 0; c < 2; c++) {
      bf16x8 pf;
      {
        int q = lane & 15;
        int e = q * 128 + c * 64 + ((lane >> 4) << 4);
        pf = *(const bf16x8*)(Psw + (e ^ ((q & 7) << 4)));
      }
      #pragma unroll
      for (int db = 0; db < 4; db++) {
        int d = db * 16 + (lane & 15);
        int e = d * 128 + c * 64 + ((lane >> 4) << 4);
        bf16x8 vf = *(const bf16x8*)(Vt + (e ^ ((d & 7) << 4)));
        accO[db] = __builtin_amdgcn_mfma_f32_16x16x32_bf16(pf, vf, accO[db], 0, 0, 0);
      }
    }
    __syncthreads();
  }
  #pragma unroll
  for (int j = 0; j < 4; j++) {
    float inv = 1.0f / Lrun[j];
    int r = base + q0 + wid * 16 + ((lane >> 4) << 2) + j;
    u16* orow = opre + (size_t)r * 1024 + h * 64;
    #pragma unroll
    for (int db = 0; db < 4; db++)
      orow[db * 16 + (lane & 15)] = f2bf(accO[db][j] * inv);
  }
}

// ---------------- OUT GEMM: [14336,1024] x per-seg Wo^T[1024,1024] -> f32 ----
// epilogue scatters rows through inverse dilation-reorder + hilbert perm
__global__ __launch_bounds__(256) void out_gemm_kernel(
    const u16* __restrict__ A, const u16* __restrict__ Bt,
    const float* __restrict__ b0, const float* __restrict__ b1,
    const float* __restrict__ b2, const int* __restrict__ perm,
    float* __restrict__ Out) {
  __shared__ char smem[32768];
  __shared__ int drow[128];
  char* As = smem;
  char* Bs = smem + 16384;
  const int tid = threadIdx.x;
  const int lane = tid & 63, wid = tid >> 6;
  const int wm = wid >> 1, wn = wid & 1;
  const int rb = blockIdx.x, nb = blockIdx.y;
  const int seg = (rb < 16) ? 0 : (rb < 48 ? 1 : 2);
  const int segpos = (seg == 0) ? 0 : (seg == 1 ? 2048 : 6144);
  const int rate = 1 << seg;
  const float* bias = (seg == 0) ? b0 : (seg == 1 ? b1 : b2);
  const size_t arow0 = (size_t)rb * 128;
  const char* Ab = (const char*)(A + arow0 * 1024);
  const char* Bb = (const char*)(Bt + ((size_t)seg * 1024 + (size_t)nb * 128) * 1024);

  f32x4 acc[4][4] = {};

  for (int kt = 0; kt < 16; kt++) {
    #pragma unroll
    for (int it = 0; it < 4; it++) {
      int p = (it * 256 + tid) * 16;
      int e = p ^ (((p >> 7) & 7) << 4);
      int row = e >> 7, col = e & 127;
      gl_lds16(Ab + (size_t)row * 2048 + kt * 128 + col, As + it * 4096 + wid * 1024);
      gl_lds16(Bb + (size_t)row * 2048 + kt * 128 + col, Bs + it * 4096 + wid * 1024);
    }
    __syncthreads();
    #pragma unroll
    for (int kc = 0; kc < 2; kc++) {
      bf16x8 af[4], bfr[4];
      #pragma unroll
      for (int m = 0; m < 4; m++) {
        int row = wm * 64 + m * 16 + (lane & 15);
        int e = row * 128 + kc * 64 + ((lane >> 4) << 4);
        af[m] = *(const bf16x8*)(As + (e ^ ((row & 7) << 4)));
      }
      #pragma unroll
      for (int n = 0; n < 4; n++) {
        int row = wn * 64 + n * 16 + (lane & 15);
        int e = row * 128 + kc * 64 + ((lane >> 4) << 4);
        bfr[n] = *(const bf16x8*)(Bs + (e ^ ((row & 7) << 4)));
      }
      #pragma unroll
      for (int m = 0; m < 4; m++)
        #pragma unroll
        for (int n = 0; n < 4; n++)
          acc[m][n] = __builtin_amdgcn_mfma_f32_16x16x32_bf16(af[m], bfr[n], acc[m][n], 0, 0, 0);
    }
    __syncthreads();
  }
  if (tid < 128) {
    int rl = (int)arow0 + tid - segpos;
    int t = (rl & (LR - 1)) * rate + (rl >> 11);
    drow[tid] = segpos + perm[segpos + t];
  }
  __syncthreads();
  float bv[4];
  #pragma unroll
  for (int n = 0; n < 4; n++) bv[n] = bias[nb * 128 + wn * 64 + n * 16 + (lane & 15)];
  #pragma unroll
  for (int m = 0; m < 4; m++)
    #pragma unroll
    for (int j = 0; j < 4; j++) {
      int r = wm * 64 + m * 16 + ((lane >> 4) << 2) + j;
      int gr = drow[r];
      float* orow = Out + (size_t)gr * 1024 + nb * 128 + wn * 64;
      #pragma unroll
      for (int n = 0; n < 4; n++)
        orow[n * 16 + (lane & 15)] = acc[m][n][j] + bv[n];
    }
}

// ---------------- launch ----------------
extern "C" void kernel_launch(void* const* d_in, const int* in_sizes, int n_in,
                              void* d_out, int out_size, void* d_ws, size_t ws_size,
                              hipStream_t stream) {
  (void)in_sizes; (void)n_in; (void)out_size;
  const float* x = (const float*)d_in[0];
  const float* wqkv0 = (const float*)d_in[3];
  const float* bqkv0 = (const float*)d_in[4];
  const float* wo0 = (const float*)d_in[5];
  const float* bo0 = (const float*)d_in[6];
  const float* wqkv1 = (const float*)d_in[7];
  const float* bqkv1 = (const float*)d_in[8];
  const float* wo1 = (const float*)d_in[9];
  const float* bo1 = (const float*)d_in[10];
  const float* wqkv2 = (const float*)d_in[11];
  const float* bqkv2 = (const float*)d_in[12];
  const float* wo2 = (const float*)d_in[13];
  const float* bo2 = (const float*)d_in[14];

  if (ws_size < 172032000ull) return;  // workspace layout below needs 172 MB
  char* ws = (char*)d_ws;
  int* perm = (int*)ws;                        //     57,344 B
  u16* xh    = (u16*)(ws + 65536);             // 29,360,128 B
  u16* wqkvt = (u16*)(ws + 29425664);          // 18,874,368 B
  u16* wot   = (u16*)(ws + 48300032);          //  6,291,456 B
  u16* qkv   = (u16*)(ws + 54591488);          // 88,080,384 B
  u16* opre  = (u16*)(ws + 142671872);         // 29,360,128 B
  float* out = (float*)d_out;

  hipMemsetAsync(opre, 0, 29360128, stream);
  hilbert_kernel<<<56, 256, 0, stream>>>(perm);
  wtrans_kernel<<<dim3(96, 32, 3), dim3(32, 8), 0, stream>>>(wqkv0, wqkv1, wqkv2, wqkvt, 1024, 3072);
  wtrans_kernel<<<dim3(32, 32, 3), dim3(32, 8), 0, stream>>>(wo0, wo1, wo2, wot, 1024, 1024);
  gather_kernel<<<14336, 256, 0, stream>>>(x, perm, xh);
  qkv_gemm_kernel<<<dim3(112, 24), 256, 0, stream>>>(xh, wqkvt, bqkv0, bqkv1, bqkv2, qkv);
  attn_kernel<<<dim3(32, 48), 256, 0, stream>>>(qkv, opre);
  out_gemm_kernel<<<dim3(112, 8), 256, 0, stream>>>(opre, wot, bo0, bo1, bo2, perm, out);
}

// Round 3
// 400.191 us; speedup vs baseline: 1.0623x; 1.0623x over previous
//
#include <hip/hip_runtime.h>
#include <stdint.h>
#include <stddef.h>

typedef unsigned short u16;
typedef short bf16x8 __attribute__((ext_vector_type(8)));
typedef float f32x4 __attribute__((ext_vector_type(4)));
typedef unsigned short ushort8v __attribute__((ext_vector_type(8)));

#define LR 2048
#define LOG2E 1.44269504088896f

__device__ __forceinline__ u16 f2bf(float f) {
  unsigned u = __float_as_uint(f);
  unsigned r = u + 0x7fffu + ((u >> 16) & 1u);
  return (u16)(r >> 16);
}

__device__ __forceinline__ void gl_lds16(const void* g, void* l) {
  __builtin_amdgcn_global_load_lds((__attribute__((address_space(1))) void*)g,
                                   (__attribute__((address_space(3))) void*)l,
                                   16, 0, 0);
}

// ---------------- Hilbert permutation (closed form, no sort) ----------------
__global__ void hilbert_kernel(int* __restrict__ perm) {
  int idx = blockIdx.x * 256 + threadIdx.x;
  if (idx >= 14336) return;
  int seg = (idx < 2048) ? 0 : (idx < 6144 ? 1 : 2);
  int segpos = (seg == 0) ? 0 : (seg == 1 ? 2048 : 6144);
  int L = 2048 << seg;
  int n = (seg == 2) ? 128 : 64;
  int t = idx - segpos;
  int d = (L == n * n) ? t : ((t < (L >> 1)) ? t : t + L);
  int x = 0, y = 0;
  for (int s = 1; s < n; s <<= 1) {
    int rx = 1 & (d >> 1);
    int ry = 1 & (d ^ rx);
    if (ry == 0) {
      if (rx == 1) { x = s - 1 - x; y = s - 1 - y; }
      int tmp = x; x = y; y = tmp;
    }
    x += s * rx; y += s * ry;
    d >>= 2;
  }
  perm[idx] = y * n + x;
}

// ---------------- weight transpose + convert: [K][N] f32 -> [N][K] bf16 ------
__global__ void wtrans_kernel(const float* __restrict__ s0, const float* __restrict__ s1,
                              const float* __restrict__ s2, u16* __restrict__ dst,
                              int K, int N) {
  const float* S = (blockIdx.z == 0) ? s0 : (blockIdx.z == 1 ? s1 : s2);
  u16* D = dst + (size_t)blockIdx.z * K * N;
  __shared__ float tl[32][33];
  int n0 = blockIdx.x * 32, k0 = blockIdx.y * 32;
  int tx = threadIdx.x, ty = threadIdx.y;  // (32,8)
  #pragma unroll
  for (int i = 0; i < 4; i++)
    tl[ty + 8 * i][tx] = S[(size_t)(k0 + ty + 8 * i) * N + n0 + tx];
  __syncthreads();
  #pragma unroll
  for (int i = 0; i < 4; i++)
    D[(size_t)(n0 + ty + 8 * i) * K + k0 + tx] = f2bf(tl[tx][ty + 8 * i]);
}

// ---------------- gather x rows: hilbert perm + dilation reorder, f32->bf16 --
__global__ void gather_kernel(const float* __restrict__ x, const int* __restrict__ perm,
                              u16* __restrict__ xh) {
  int rr = blockIdx.x;
  int seg = (rr < 2048) ? 0 : (rr < 6144 ? 1 : 2);
  int segpos = (seg == 0) ? 0 : (seg == 1 ? 2048 : 6144);
  int rate = 1 << seg;
  int rl = rr - segpos;
  int t = (rl & (LR - 1)) * rate + (rl >> 11);
  int orig = segpos + perm[segpos + t];
  float4 v = *((const float4*)(x + (size_t)orig * 1024) + threadIdx.x);
  ushort4 o;
  o.x = f2bf(v.x); o.y = f2bf(v.y); o.z = f2bf(v.z); o.w = f2bf(v.w);
  *((ushort4*)(xh + (size_t)rr * 1024) + threadIdx.x) = o;
}

// ---------------- QKV GEMM: [14336,1024] x per-seg W^T[3072,1024] -> bf16 ----
__global__ __launch_bounds__(256) void qkv_gemm_kernel(
    const u16* __restrict__ A, const u16* __restrict__ Bt,
    const float* __restrict__ b0, const float* __restrict__ b1,
    const float* __restrict__ b2, u16* __restrict__ C) {
  __shared__ char smem[35328];
  char* As = smem;           // [128][64] bf16, swizzled
  char* Bs = smem + 16384;
  const int tid = threadIdx.x;
  const int lane = tid & 63, wid = tid >> 6;
  const int wm = wid >> 1, wn = wid & 1;
  const int rb = blockIdx.x, nb = blockIdx.y;
  const int seg = (rb < 16) ? 0 : (rb < 48 ? 1 : 2);
  const float* bias = (seg == 0) ? b0 : (seg == 1 ? b1 : b2);
  const size_t arow0 = (size_t)rb * 128;
  const char* Ab = (const char*)(A + arow0 * 1024);
  const char* Bb = (const char*)(Bt + ((size_t)seg * 3072 + (size_t)nb * 128) * 1024);

  f32x4 acc[4][4] = {};

  for (int kt = 0; kt < 16; kt++) {
    #pragma unroll
    for (int it = 0; it < 4; it++) {
      int p = (it * 256 + tid) * 16;
      int e = p ^ (((p >> 7) & 7) << 4);
      int row = e >> 7, col = e & 127;
      gl_lds16(Ab + (size_t)row * 2048 + kt * 128 + col, As + it * 4096 + wid * 1024);
      gl_lds16(Bb + (size_t)row * 2048 + kt * 128 + col, Bs + it * 4096 + wid * 1024);
    }
    __syncthreads();
    #pragma unroll
    for (int kc = 0; kc < 2; kc++) {
      bf16x8 af[4], bfr[4];
      #pragma unroll
      for (int m = 0; m < 4; m++) {
        int row = wm * 64 + m * 16 + (lane & 15);
        int e = row * 128 + kc * 64 + ((lane >> 4) << 4);
        af[m] = *(const bf16x8*)(As + (e ^ ((row & 7) << 4)));
      }
      #pragma unroll
      for (int n = 0; n < 4; n++) {
        int row = wn * 64 + n * 16 + (lane & 15);
        int e = row * 128 + kc * 64 + ((lane >> 4) << 4);
        bfr[n] = *(const bf16x8*)(Bs + (e ^ ((row & 7) << 4)));
      }
      #pragma unroll
      for (int m = 0; m < 4; m++)
        #pragma unroll
        for (int n = 0; n < 4; n++)
          acc[m][n] = __builtin_amdgcn_mfma_f32_16x16x32_bf16(af[m], bfr[n], acc[m][n], 0, 0, 0);
    }
    __syncthreads();
  }
  float bv[4];
  #pragma unroll
  for (int n = 0; n < 4; n++) bv[n] = bias[nb * 128 + wn * 64 + n * 16 + (lane & 15)];
  #pragma unroll
  for (int m = 0; m < 4; m++)
    #pragma unroll
    for (int n = 0; n < 4; n++)
      #pragma unroll
      for (int j = 0; j < 4; j++) {
        int r = wm * 64 + m * 16 + ((lane >> 4) << 2) + j;
        int c = wn * 64 + n * 16 + (lane & 15);
        *(u16*)(smem + r * 272 + c * 2) = f2bf(acc[m][n][j] + bv[n]);
      }
  __syncthreads();
  #pragma unroll
  for (int it = 0; it < 8; it++) {
    int ci = it * 256 + tid;
    int row = ci >> 4, c16 = ci & 15;
    bf16x8 vv = *(const bf16x8*)(smem + row * 272 + c16 * 16);
    u16* crow = C + (arow0 + row) * 3072 + nb * 128;
    *(bf16x8*)((char*)crow + c16 * 16) = vv;
  }
}

// ---------------- flash attention v2: double-buffered K/V, Q hoisted, --------
// ---------------- defer-max, conflict-free Vt transpose writes ---------------
__global__ __launch_bounds__(256) void attn_kernel(const u16* __restrict__ qkv,
                                                   u16* __restrict__ opre) {
  __shared__ char smem[49152];
  char* Qs = smem;                      // [64 q][64 d] swz
  // K buffers at smem+8192 + cur*8192; Vt buffers at smem+24576 + cur*8192
  const int tid = threadIdx.x;
  const int lane = tid & 63;
  const int wid = tid >> 6;
  char* Psw = smem + 40960 + wid * 2048;  // per-wave [16 q][64 key]
  const int by = blockIdx.y;
  const int seg = by >> 4, h = by & 15;
  const int segrow = (seg == 0) ? 0 : (seg == 1 ? 2048 : 6144);
  const int rate = 1 << seg;
  const int off = h & (rate - 1);
  const int base = segrow + off * LR;   // head's contiguous 2048 rows
  const int q0 = blockIdx.x * 64;
  const char* qb = (const char*)qkv;

  // V transpose mapping: thread owns 2 keys x 8 d
  const int vkey0 = 2 * (tid & 31);
  const int vd0 = (tid >> 5) * 8;

  // ---- prologue: stage Q + K0 (gl_lds), load V0 to regs ----
  #pragma unroll
  for (int it = 0; it < 2; it++) {
    int p = (it * 256 + tid) * 16;
    int e = p ^ (((p >> 7) & 7) << 4);
    int row = e >> 7, col = e & 127;
    gl_lds16(qb + (size_t)(base + q0 + row) * 6144 + h * 128 + col,
             Qs + it * 4096 + wid * 1024);
    gl_lds16(qb + (size_t)(base + row) * 6144 + 2048 + h * 128 + col,
             smem + 8192 + it * 4096 + wid * 1024);
  }
  ushort8v v0r = *(const ushort8v*)(qb + (size_t)(base + vkey0) * 6144 + 4096 + h * 128 + vd0 * 2);
  ushort8v v1r = *(const ushort8v*)(qb + (size_t)(base + vkey0 + 1) * 6144 + 4096 + h * 128 + vd0 * 2);
  __syncthreads();
  // write Vt[0]
  #pragma unroll
  for (int dd = 0; dd < 8; dd++) {
    int d = vd0 + dd;
    unsigned val = (unsigned)(u16)v0r[dd] | ((unsigned)(u16)v1r[dd] << 16);
    int addr = d * 128 + vkey0 * 2;
    *(unsigned*)(smem + 24576 + (addr ^ ((d & 7) << 4))) = val;
  }
  // hoist Q fragments (loop-invariant)
  bf16x8 qf[2];
  #pragma unroll
  for (int kc = 0; kc < 2; kc++) {
    int qrow = wid * 16 + (lane & 15);
    int e = qrow * 128 + kc * 64 + ((lane >> 4) << 4);
    qf[kc] = *(const bf16x8*)(Qs + (e ^ ((qrow & 7) << 4)));
  }
  __syncthreads();

  float Mrun[4] = {-INFINITY, -INFINITY, -INFINITY, -INFINITY};
  float Lrun[4] = {0.f, 0.f, 0.f, 0.f};
  f32x4 accO[4] = {};
  const float K1 = 0.125f * LOG2E;

  for (int kt = 0; kt < 32; kt++) {
    const int cur = kt & 1;
    const int nxt = cur ^ 1;
    char* Ks = smem + 8192 + (cur << 13);
    char* Vt = smem + 24576 + (cur << 13);
    char* Ksn = smem + 8192 + (nxt << 13);
    char* Vtn = smem + 24576 + (nxt << 13);
    ushort8v nv0, nv1;
    if (kt < 31) {  // issue next tile's loads early (T14)
      #pragma unroll
      for (int it = 0; it < 2; it++) {
        int p = (it * 256 + tid) * 16;
        int e = p ^ (((p >> 7) & 7) << 4);
        int row = e >> 7, col = e & 127;
        gl_lds16(qb + (size_t)(base + (kt + 1) * 64 + row) * 6144 + 2048 + h * 128 + col,
                 Ksn + it * 4096 + wid * 1024);
      }
      nv0 = *(const ushort8v*)(qb + (size_t)(base + (kt + 1) * 64 + vkey0) * 6144 + 4096 + h * 128 + vd0 * 2);
      nv1 = *(const ushort8v*)(qb + (size_t)(base + (kt + 1) * 64 + vkey0 + 1) * 6144 + 4096 + h * 128 + vd0 * 2);
    }
    // QK^T
    f32x4 sacc[4] = {};
    #pragma unroll
    for (int kc = 0; kc < 2; kc++)
      #pragma unroll
      for (int n = 0; n < 4; n++) {
        int krow = n * 16 + (lane & 15);
        int e = krow * 128 + kc * 64 + ((lane >> 4) << 4);
        bf16x8 kf = *(const bf16x8*)(Ks + (e ^ ((krow & 7) << 4)));
        sacc[n] = __builtin_amdgcn_mfma_f32_16x16x32_bf16(qf[kc], kf, sacc[n], 0, 0, 0);
      }
    // online softmax with defer-max (T13)
    float pb[4][4];
    #pragma unroll
    for (int j = 0; j < 4; j++) {
      float mr = fmaxf(fmaxf(sacc[0][j], sacc[1][j]), fmaxf(sacc[2][j], sacc[3][j]));
      #pragma unroll
      for (int msk = 1; msk < 16; msk <<= 1) mr = fmaxf(mr, __shfl_xor(mr, msk, 16));
      float m = mr * 0.125f;
      if (!__all(m - Mrun[j] <= 8.0f)) {
        float mnew = fmaxf(Mrun[j], m);
        float rf = exp2f((Mrun[j] - mnew) * LOG2E);
        Lrun[j] *= rf;
        accO[0][j] *= rf; accO[1][j] *= rf; accO[2][j] *= rf; accO[3][j] *= rf;
        Mrun[j] = mnew;
      }
      float c2 = Mrun[j] * LOG2E;
      float ssum = 0.f;
      #pragma unroll
      for (int n = 0; n < 4; n++) {
        float pv = exp2f(sacc[n][j] * K1 - c2);
        pb[n][j] = pv; ssum += pv;
      }
      #pragma unroll
      for (int msk = 1; msk < 16; msk <<= 1) ssum += __shfl_xor(ssum, msk, 16);
      Lrun[j] += ssum;
    }
    // P -> per-wave LDS (bf16)
    #pragma unroll
    for (int n = 0; n < 4; n++)
      #pragma unroll
      for (int j = 0; j < 4; j++) {
        int q = ((lane >> 4) << 2) + j;
        int addr = q * 128 + (n * 16 + (lane & 15)) * 2;
        *(u16*)(Psw + (addr ^ ((q & 7) << 4))) = f2bf(pb[n][j]);
      }
    // PV
    #pragma unroll
    for (int c = 0; c < 2; c++) {
      bf16x8 pf;
      {
        int q = lane & 15;
        int e = q * 128 + c * 64 + ((lane >> 4) << 4);
        pf = *(const bf16x8*)(Psw + (e ^ ((q & 7) << 4)));
      }
      #pragma unroll
      for (int db = 0; db < 4; db++) {
        int d = db * 16 + (lane & 15);
        int e = d * 128 + c * 64 + ((lane >> 4) << 4);
        bf16x8 vf = *(const bf16x8*)(Vt + (e ^ ((d & 7) << 4)));
        accO[db] = __builtin_amdgcn_mfma_f32_16x16x32_bf16(pf, vf, accO[db], 0, 0, 0);
      }
    }
    // write next V tile late (loads had the whole compute phase in flight)
    if (kt < 31) {
      #pragma unroll
      for (int dd = 0; dd < 8; dd++) {
        int d = vd0 + dd;
        unsigned val = (unsigned)(u16)nv0[dd] | ((unsigned)(u16)nv1[dd] << 16);
        int addr = d * 128 + vkey0 * 2;
        *(unsigned*)(Vtn + (addr ^ ((d & 7) << 4))) = val;
      }
    }
    __syncthreads();
  }
  #pragma unroll
  for (int j = 0; j < 4; j++) {
    float inv = 1.0f / Lrun[j];
    int r = base + q0 + wid * 16 + ((lane >> 4) << 2) + j;
    u16* orow = opre + (size_t)r * 1024 + h * 64;
    #pragma unroll
    for (int db = 0; db < 4; db++)
      orow[db * 16 + (lane & 15)] = f2bf(accO[db][j] * inv);
  }
}

// ---------------- OUT GEMM: [14336,1024] x per-seg Wo^T[1024,1024] -> f32 ----
__global__ __launch_bounds__(256) void out_gemm_kernel(
    const u16* __restrict__ A, const u16* __restrict__ Bt,
    const float* __restrict__ b0, const float* __restrict__ b1,
    const float* __restrict__ b2, const int* __restrict__ perm,
    float* __restrict__ Out) {
  __shared__ char smem[32768];
  __shared__ int drow[128];
  char* As = smem;
  char* Bs = smem + 16384;
  const int tid = threadIdx.x;
  const int lane = tid & 63, wid = tid >> 6;
  const int wm = wid >> 1, wn = wid & 1;
  const int rb = blockIdx.x, nb = blockIdx.y;
  const int seg = (rb < 16) ? 0 : (rb < 48 ? 1 : 2);
  const int segpos = (seg == 0) ? 0 : (seg == 1 ? 2048 : 6144);
  const int rate = 1 << seg;
  const float* bias = (seg == 0) ? b0 : (seg == 1 ? b1 : b2);
  const size_t arow0 = (size_t)rb * 128;
  const char* Ab = (const char*)(A + arow0 * 1024);
  const char* Bb = (const char*)(Bt + ((size_t)seg * 1024 + (size_t)nb * 128) * 1024);

  f32x4 acc[4][4] = {};

  for (int kt = 0; kt < 16; kt++) {
    #pragma unroll
    for (int it = 0; it < 4; it++) {
      int p = (it * 256 + tid) * 16;
      int e = p ^ (((p >> 7) & 7) << 4);
      int row = e >> 7, col = e & 127;
      gl_lds16(Ab + (size_t)row * 2048 + kt * 128 + col, As + it * 4096 + wid * 1024);
      gl_lds16(Bb + (size_t)row * 2048 + kt * 128 + col, Bs + it * 4096 + wid * 1024);
    }
    __syncthreads();
    #pragma unroll
    for (int kc = 0; kc < 2; kc++) {
      bf16x8 af[4], bfr[4];
      #pragma unroll
      for (int m = 0; m < 4; m++) {
        int row = wm * 64 + m * 16 + (lane & 15);
        int e = row * 128 + kc * 64 + ((lane >> 4) << 4);
        af[m] = *(const bf16x8*)(As + (e ^ ((row & 7) << 4)));
      }
      #pragma unroll
      for (int n = 0; n < 4; n++) {
        int row = wn * 64 + n * 16 + (lane & 15);
        int e = row * 128 + kc * 64 + ((lane >> 4) << 4);
        bfr[n] = *(const bf16x8*)(Bs + (e ^ ((row & 7) << 4)));
      }
      #pragma unroll
      for (int m = 0; m < 4; m++)
        #pragma unroll
        for (int n = 0; n < 4; n++)
          acc[m][n] = __builtin_amdgcn_mfma_f32_16x16x32_bf16(af[m], bfr[n], acc[m][n], 0, 0, 0);
    }
    __syncthreads();
  }
  if (tid < 128) {
    int rl = (int)arow0 + tid - segpos;
    int t = (rl & (LR - 1)) * rate + (rl >> 11);
    drow[tid] = segpos + perm[segpos + t];
  }
  __syncthreads();
  float bv[4];
  #pragma unroll
  for (int n = 0; n < 4; n++) bv[n] = bias[nb * 128 + wn * 64 + n * 16 + (lane & 15)];
  #pragma unroll
  for (int m = 0; m < 4; m++)
    #pragma unroll
    for (int j = 0; j < 4; j++) {
      int r = wm * 64 + m * 16 + ((lane >> 4) << 2) + j;
      int gr = drow[r];
      float* orow = Out + (size_t)gr * 1024 + nb * 128 + wn * 64;
      #pragma unroll
      for (int n = 0; n < 4; n++)
        orow[n * 16 + (lane & 15)] = acc[m][n][j] + bv[n];
    }
}

// ---------------- launch ----------------
extern "C" void kernel_launch(void* const* d_in, const int* in_sizes, int n_in,
                              void* d_out, int out_size, void* d_ws, size_t ws_size,
                              hipStream_t stream) {
  (void)in_sizes; (void)n_in; (void)out_size;
  const float* x = (const float*)d_in[0];
  const float* wqkv0 = (const float*)d_in[3];
  const float* bqkv0 = (const float*)d_in[4];
  const float* wo0 = (const float*)d_in[5];
  const float* bo0 = (const float*)d_in[6];
  const float* wqkv1 = (const float*)d_in[7];
  const float* bqkv1 = (const float*)d_in[8];
  const float* wo1 = (const float*)d_in[9];
  const float* bo1 = (const float*)d_in[10];
  const float* wqkv2 = (const float*)d_in[11];
  const float* bqkv2 = (const float*)d_in[12];
  const float* wo2 = (const float*)d_in[13];
  const float* bo2 = (const float*)d_in[14];

  if (ws_size < 172032000ull) return;
  char* ws = (char*)d_ws;
  int* perm = (int*)ws;                        //     57,344 B
  u16* xh    = (u16*)(ws + 65536);             // 29,360,128 B
  u16* wqkvt = (u16*)(ws + 29425664);          // 18,874,368 B
  u16* wot   = (u16*)(ws + 48300032);          //  6,291,456 B
  u16* qkv   = (u16*)(ws + 54591488);          // 88,080,384 B
  u16* opre  = (u16*)(ws + 142671872);         // 29,360,128 B
  float* out = (float*)d_out;

  (void)hipMemsetAsync(opre, 0, 29360128, stream);
  hilbert_kernel<<<56, 256, 0, stream>>>(perm);
  wtrans_kernel<<<dim3(96, 32, 3), dim3(32, 8), 0, stream>>>(wqkv0, wqkv1, wqkv2, wqkvt, 1024, 3072);
  wtrans_kernel<<<dim3(32, 32, 3), dim3(32, 8), 0, stream>>>(wo0, wo1, wo2, wot, 1024, 1024);
  gather_kernel<<<14336, 256, 0, stream>>>(x, perm, xh);
  qkv_gemm_kernel<<<dim3(112, 24), 256, 0, stream>>>(xh, wqkvt, bqkv0, bqkv1, bqkv2, qkv);
  attn_kernel<<<dim3(32, 48), 256, 0, stream>>>(qkv, opre);
  out_gemm_kernel<<<dim3(112, 8), 256, 0, stream>>>(opre, wot, bo0, bo1, bo2, perm, out);
}

// Round 4
// 378.494 us; speedup vs baseline: 1.1232x; 1.0573x over previous
//
#include <hip/hip_runtime.h>
#include <stdint.h>
#include <stddef.h>

typedef unsigned short u16;
typedef short bf16x8 __attribute__((ext_vector_type(8)));
typedef float f32x4 __attribute__((ext_vector_type(4)));
typedef unsigned short ushort8v __attribute__((ext_vector_type(8)));

#define LR 2048
#define LOG2E 1.44269504088896f

__device__ __forceinline__ u16 f2bf(float f) {
  unsigned u = __float_as_uint(f);
  unsigned r = u + 0x7fffu + ((u >> 16) & 1u);
  return (u16)(r >> 16);
}

// single-float bf16 convert in 1 VALU op (RNE), for hot loops
__device__ __forceinline__ u16 f2bf_hw(float f) {
  unsigned r;
  asm("v_cvt_pk_bf16_f32 %0, %1, %2" : "=v"(r) : "v"(f), "v"(f));
  return (u16)(r & 0xffffu);
}

__device__ __forceinline__ void gl_lds16(const void* g, void* l) {
  __builtin_amdgcn_global_load_lds((__attribute__((address_space(1))) void*)g,
                                   (__attribute__((address_space(3))) void*)l,
                                   16, 0, 0);
}

// ---------------- Hilbert permutation (closed form, no sort) ----------------
__global__ void hilbert_kernel(int* __restrict__ perm) {
  int idx = blockIdx.x * 256 + threadIdx.x;
  if (idx >= 14336) return;
  int seg = (idx < 2048) ? 0 : (idx < 6144 ? 1 : 2);
  int segpos = (seg == 0) ? 0 : (seg == 1 ? 2048 : 6144);
  int L = 2048 << seg;
  int n = (seg == 2) ? 128 : 64;
  int t = idx - segpos;
  int d = (L == n * n) ? t : ((t < (L >> 1)) ? t : t + L);
  int x = 0, y = 0;
  for (int s = 1; s < n; s <<= 1) {
    int rx = 1 & (d >> 1);
    int ry = 1 & (d ^ rx);
    if (ry == 0) {
      if (rx == 1) { x = s - 1 - x; y = s - 1 - y; }
      int tmp = x; x = y; y = tmp;
    }
    x += s * rx; y += s * ry;
    d >>= 2;
  }
  perm[idx] = y * n + x;
}

// ---------------- weight transpose + convert: [K][N] f32 -> [N][K] bf16 ------
// do_remap=1: permute K-columns head-wise so per-dilation-block K is contiguous
__global__ void wtrans_kernel(const float* __restrict__ s0, const float* __restrict__ s1,
                              const float* __restrict__ s2, u16* __restrict__ dst,
                              int K, int N, int do_remap) {
  const int seg = blockIdx.z;
  const float* S = (seg == 0) ? s0 : (seg == 1 ? s1 : s2);
  u16* D = dst + (size_t)seg * K * N;
  __shared__ float tl[32][33];
  int n0 = blockIdx.x * 32, k0 = blockIdx.y * 32;
  int tx = threadIdx.x, ty = threadIdx.y;  // (32,8)
  #pragma unroll
  for (int i = 0; i < 4; i++)
    tl[ty + 8 * i][tx] = S[(size_t)(k0 + ty + 8 * i) * N + n0 + tx];
  __syncthreads();
  int kk = k0 + tx;
  if (do_remap) {
    int rate = 1 << seg;
    int h = kk >> 6;
    int h2 = (h & (rate - 1)) * (16 >> seg) + (h >> seg);
    kk = h2 * 64 + (kk & 63);
  }
  #pragma unroll
  for (int i = 0; i < 4; i++)
    D[(size_t)(n0 + ty + 8 * i) * K + kk] = f2bf(tl[tx][ty + 8 * i]);
}

// ---------------- gather x rows: hilbert perm + dilation reorder, f32->bf16 --
__global__ void gather_kernel(const float* __restrict__ x, const int* __restrict__ perm,
                              u16* __restrict__ xh) {
  int rr = blockIdx.x;
  int seg = (rr < 2048) ? 0 : (rr < 6144 ? 1 : 2);
  int segpos = (seg == 0) ? 0 : (seg == 1 ? 2048 : 6144);
  int rate = 1 << seg;
  int rl = rr - segpos;
  int t = (rl & (LR - 1)) * rate + (rl >> 11);
  int orig = segpos + perm[segpos + t];
  float4 v = *((const float4*)(x + (size_t)orig * 1024) + threadIdx.x);
  ushort4 o;
  o.x = f2bf(v.x); o.y = f2bf(v.y); o.z = f2bf(v.z); o.w = f2bf(v.w);
  *((ushort4*)(xh + (size_t)rr * 1024) + threadIdx.x) = o;
}

// ---------------- QKV GEMM: [14336,1024] x per-seg W^T[3072,1024] -> bf16 ----
__global__ __launch_bounds__(256) void qkv_gemm_kernel(
    const u16* __restrict__ A, const u16* __restrict__ Bt,
    const float* __restrict__ b0, const float* __restrict__ b1,
    const float* __restrict__ b2, u16* __restrict__ C) {
  __shared__ char smem[35328];
  char* As = smem;           // [128][64] bf16, swizzled
  char* Bs = smem + 16384;
  const int tid = threadIdx.x;
  const int lane = tid & 63, wid = tid >> 6;
  const int wm = wid >> 1, wn = wid & 1;
  const int rb = blockIdx.x, nb = blockIdx.y;
  const int seg = (rb < 16) ? 0 : (rb < 48 ? 1 : 2);
  const float* bias = (seg == 0) ? b0 : (seg == 1 ? b1 : b2);
  const size_t arow0 = (size_t)rb * 128;
  const char* Ab = (const char*)(A + arow0 * 1024);
  const char* Bb = (const char*)(Bt + ((size_t)seg * 3072 + (size_t)nb * 128) * 1024);

  f32x4 acc[4][4] = {};

  for (int kt = 0; kt < 16; kt++) {
    #pragma unroll
    for (int it = 0; it < 4; it++) {
      int p = (it * 256 + tid) * 16;
      int e = p ^ (((p >> 7) & 7) << 4);
      int row = e >> 7, col = e & 127;
      gl_lds16(Ab + (size_t)row * 2048 + kt * 128 + col, As + it * 4096 + wid * 1024);
      gl_lds16(Bb + (size_t)row * 2048 + kt * 128 + col, Bs + it * 4096 + wid * 1024);
    }
    __syncthreads();
    #pragma unroll
    for (int kc = 0; kc < 2; kc++) {
      bf16x8 af[4], bfr[4];
      #pragma unroll
      for (int m = 0; m < 4; m++) {
        int row = wm * 64 + m * 16 + (lane & 15);
        int e = row * 128 + kc * 64 + ((lane >> 4) << 4);
        af[m] = *(const bf16x8*)(As + (e ^ ((row & 7) << 4)));
      }
      #pragma unroll
      for (int n = 0; n < 4; n++) {
        int row = wn * 64 + n * 16 + (lane & 15);
        int e = row * 128 + kc * 64 + ((lane >> 4) << 4);
        bfr[n] = *(const bf16x8*)(Bs + (e ^ ((row & 7) << 4)));
      }
      #pragma unroll
      for (int m = 0; m < 4; m++)
        #pragma unroll
        for (int n = 0; n < 4; n++)
          acc[m][n] = __builtin_amdgcn_mfma_f32_16x16x32_bf16(af[m], bfr[n], acc[m][n], 0, 0, 0);
    }
    __syncthreads();
  }
  float bv[4];
  #pragma unroll
  for (int n = 0; n < 4; n++) bv[n] = bias[nb * 128 + wn * 64 + n * 16 + (lane & 15)];
  #pragma unroll
  for (int m = 0; m < 4; m++)
    #pragma unroll
    for (int n = 0; n < 4; n++)
      #pragma unroll
      for (int j = 0; j < 4; j++) {
        int r = wm * 64 + m * 16 + ((lane >> 4) << 2) + j;
        int c = wn * 64 + n * 16 + (lane & 15);
        *(u16*)(smem + r * 272 + c * 2) = f2bf(acc[m][n][j] + bv[n]);
      }
  __syncthreads();
  #pragma unroll
  for (int it = 0; it < 8; it++) {
    int ci = it * 256 + tid;
    int row = ci >> 4, c16 = ci & 15;
    bf16x8 vv = *(const bf16x8*)(smem + row * 272 + c16 * 16);
    u16* crow = C + (arow0 + row) * 3072 + nb * 128;
    *(bf16x8*)((char*)crow + c16 * 16) = vv;
  }
}

// ---------------- flash attention v3: Psw overlays Q staging (4 blocks/CU), --
// ---------------- cvt_pk bf16 pack, head-remapped output columns -------------
__global__ __launch_bounds__(256) void attn_kernel(const u16* __restrict__ qkv,
                                                   u16* __restrict__ opre) {
  __shared__ char smem[40960];
  char* Qs = smem;                      // [64 q][64 d] swz -- reused as Psw after prologue
  // K buffers at smem+8192 + cur*8192; Vt buffers at smem+24576 + cur*8192
  const int tid = threadIdx.x;
  const int lane = tid & 63;
  const int wid = tid >> 6;
  char* Psw = smem + wid * 2048;        // per-wave [16 q][64 key] (overlay on Qs)
  const int by = blockIdx.y;
  const int seg = by >> 4, h = by & 15;
  const int segrow = (seg == 0) ? 0 : (seg == 1 ? 2048 : 6144);
  const int rate = 1 << seg;
  const int off = h & (rate - 1);
  const int base = segrow + off * LR;   // head's contiguous 2048 rows
  const int h_col = off * (16 >> seg) + (h >> seg);  // remapped output head slot
  const int q0 = blockIdx.x * 64;
  const char* qb = (const char*)qkv;

  // V transpose mapping: thread owns 2 keys x 8 d
  const int vkey0 = 2 * (tid & 31);
  const int vd0 = (tid >> 5) * 8;

  // ---- prologue: stage Q + K0 (gl_lds), load V0 to regs ----
  #pragma unroll
  for (int it = 0; it < 2; it++) {
    int p = (it * 256 + tid) * 16;
    int e = p ^ (((p >> 7) & 7) << 4);
    int row = e >> 7, col = e & 127;
    gl_lds16(qb + (size_t)(base + q0 + row) * 6144 + h * 128 + col,
             Qs + it * 4096 + wid * 1024);
    gl_lds16(qb + (size_t)(base + row) * 6144 + 2048 + h * 128 + col,
             smem + 8192 + it * 4096 + wid * 1024);
  }
  ushort8v v0r = *(const ushort8v*)(qb + (size_t)(base + vkey0) * 6144 + 4096 + h * 128 + vd0 * 2);
  ushort8v v1r = *(const ushort8v*)(qb + (size_t)(base + vkey0 + 1) * 6144 + 4096 + h * 128 + vd0 * 2);
  __syncthreads();
  // write Vt[0]
  #pragma unroll
  for (int dd = 0; dd < 8; dd++) {
    int d = vd0 + dd;
    unsigned val = (unsigned)(u16)v0r[dd] | ((unsigned)(u16)v1r[dd] << 16);
    int addr = d * 128 + vkey0 * 2;
    *(unsigned*)(smem + 24576 + (addr ^ ((d & 7) << 4))) = val;
  }
  // hoist Q fragments (loop-invariant); Qs region is free after this
  bf16x8 qf[2];
  #pragma unroll
  for (int kc = 0; kc < 2; kc++) {
    int qrow = wid * 16 + (lane & 15);
    int e = qrow * 128 + kc * 64 + ((lane >> 4) << 4);
    qf[kc] = *(const bf16x8*)(Qs + (e ^ ((qrow & 7) << 4)));
  }
  __syncthreads();

  float Mrun[4] = {-INFINITY, -INFINITY, -INFINITY, -INFINITY};
  float Lrun[4] = {0.f, 0.f, 0.f, 0.f};
  f32x4 accO[4] = {};
  const float K1 = 0.125f * LOG2E;

  for (int kt = 0; kt < 32; kt++) {
    const int cur = kt & 1;
    const int nxt = cur ^ 1;
    char* Ks = smem + 8192 + (cur << 13);
    char* Vt = smem + 24576 + (cur << 13);
    char* Ksn = smem + 8192 + (nxt << 13);
    char* Vtn = smem + 24576 + (nxt << 13);
    ushort8v nv0, nv1;
    if (kt < 31) {  // issue next tile's loads early (T14)
      #pragma unroll
      for (int it = 0; it < 2; it++) {
        int p = (it * 256 + tid) * 16;
        int e = p ^ (((p >> 7) & 7) << 4);
        int row = e >> 7, col = e & 127;
        gl_lds16(qb + (size_t)(base + (kt + 1) * 64 + row) * 6144 + 2048 + h * 128 + col,
                 Ksn + it * 4096 + wid * 1024);
      }
      nv0 = *(const ushort8v*)(qb + (size_t)(base + (kt + 1) * 64 + vkey0) * 6144 + 4096 + h * 128 + vd0 * 2);
      nv1 = *(const ushort8v*)(qb + (size_t)(base + (kt + 1) * 64 + vkey0 + 1) * 6144 + 4096 + h * 128 + vd0 * 2);
    }
    // QK^T
    f32x4 sacc[4] = {};
    #pragma unroll
    for (int kc = 0; kc < 2; kc++)
      #pragma unroll
      for (int n = 0; n < 4; n++) {
        int krow = n * 16 + (lane & 15);
        int e = krow * 128 + kc * 64 + ((lane >> 4) << 4);
        bf16x8 kf = *(const bf16x8*)(Ks + (e ^ ((krow & 7) << 4)));
        sacc[n] = __builtin_amdgcn_mfma_f32_16x16x32_bf16(qf[kc], kf, sacc[n], 0, 0, 0);
      }
    // online softmax with defer-max (T13)
    float pb[4][4];
    #pragma unroll
    for (int j = 0; j < 4; j++) {
      float mr = fmaxf(fmaxf(sacc[0][j], sacc[1][j]), fmaxf(sacc[2][j], sacc[3][j]));
      #pragma unroll
      for (int msk = 1; msk < 16; msk <<= 1) mr = fmaxf(mr, __shfl_xor(mr, msk, 16));
      float m = mr * 0.125f;
      if (!__all(m - Mrun[j] <= 8.0f)) {
        float mnew = fmaxf(Mrun[j], m);
        float rf = exp2f((Mrun[j] - mnew) * LOG2E);
        Lrun[j] *= rf;
        accO[0][j] *= rf; accO[1][j] *= rf; accO[2][j] *= rf; accO[3][j] *= rf;
        Mrun[j] = mnew;
      }
      float c2 = Mrun[j] * LOG2E;
      float ssum = 0.f;
      #pragma unroll
      for (int n = 0; n < 4; n++) {
        float pv = exp2f(sacc[n][j] * K1 - c2);
        pb[n][j] = pv; ssum += pv;
      }
      #pragma unroll
      for (int msk = 1; msk < 16; msk <<= 1) ssum += __shfl_xor(ssum, msk, 16);
      Lrun[j] += ssum;
    }
    // P -> per-wave LDS (bf16, 1-op convert)
    #pragma unroll
    for (int n = 0; n < 4; n++)
      #pragma unroll
      for (int j = 0; j < 4; j++) {
        int q = ((lane >> 4) << 2) + j;
        int addr = q * 128 + (n * 16 + (lane & 15)) * 2;
        *(u16*)(Psw + (addr ^ ((q & 7) << 4))) = f2bf_hw(pb[n][j]);
      }
    // PV
    #pragma unroll
    for (int c = 0; c < 2; c++) {
      bf16x8 pf;
      {
        int q = lane & 15;
        int e = q * 128 + c * 64 + ((lane >> 4) << 4);
        pf = *(const bf16x8*)(Psw + (e ^ ((q & 7) << 4)));
      }
      #pragma unroll
      for (int db = 0; db < 4; db++) {
        int d = db * 16 + (lane & 15);
        int e = d * 128 + c * 64 + ((lane >> 4) << 4);
        bf16x8 vf = *(const bf16x8*)(Vt + (e ^ ((d & 7) << 4)));
        accO[db] = __builtin_amdgcn_mfma_f32_16x16x32_bf16(pf, vf, accO[db], 0, 0, 0);
      }
    }
    // write next V tile late (loads had the whole compute phase in flight)
    if (kt < 31) {
      #pragma unroll
      for (int dd = 0; dd < 8; dd++) {
        int d = vd0 + dd;
        unsigned val = (unsigned)(u16)nv0[dd] | ((unsigned)(u16)nv1[dd] << 16);
        int addr = d * 128 + vkey0 * 2;
        *(unsigned*)(Vtn + (addr ^ ((d & 7) << 4))) = val;
      }
    }
    __syncthreads();
  }
  #pragma unroll
  for (int j = 0; j < 4; j++) {
    float inv = 1.0f / Lrun[j];
    int r = base + q0 + wid * 16 + ((lane >> 4) << 2) + j;
    u16* orow = opre + (size_t)r * 1024 + h_col * 64;
    #pragma unroll
    for (int db = 0; db < 4; db++)
      orow[db * 16 + (lane & 15)] = f2bf_hw(accO[db][j] * inv);
  }
}

// ---------------- OUT GEMM: residue-sparse [14336,1024] x Wo^T -> f32 --------
// head-remapped opre => valid K-range contiguous per row-block: 16>>seg k-tiles
__global__ __launch_bounds__(256) void out_gemm_kernel(
    const u16* __restrict__ A, const u16* __restrict__ Bt,
    const float* __restrict__ b0, const float* __restrict__ b1,
    const float* __restrict__ b2, const int* __restrict__ perm,
    float* __restrict__ Out) {
  __shared__ char smem[32768];
  __shared__ int drow[128];
  char* As = smem;
  char* Bs = smem + 16384;
  const int tid = threadIdx.x;
  const int lane = tid & 63, wid = tid >> 6;
  const int wm = wid >> 1, wn = wid & 1;
  const int rb = blockIdx.x, nb = blockIdx.y;
  const int seg = (rb < 16) ? 0 : (rb < 48 ? 1 : 2);
  const int segpos = (seg == 0) ? 0 : (seg == 1 ? 2048 : 6144);
  const int rate = 1 << seg;
  const float* bias = (seg == 0) ? b0 : (seg == 1 ? b1 : b2);
  const size_t arow0 = (size_t)rb * 128;
  const char* Ab = (const char*)(A + arow0 * 1024);
  const char* Bb = (const char*)(Bt + ((size_t)seg * 1024 + (size_t)nb * 128) * 1024);

  // storage block within segment -> contiguous valid K-range
  const int blk = (int)(arow0 - segpos) >> 11;
  const int ktpb = 16 >> seg;
  const int kt0 = blk * ktpb;

  f32x4 acc[4][4] = {};

  for (int kt = kt0; kt < kt0 + ktpb; kt++) {
    #pragma unroll
    for (int it = 0; it < 4; it++) {
      int p = (it * 256 + tid) * 16;
      int e = p ^ (((p >> 7) & 7) << 4);
      int row = e >> 7, col = e & 127;
      gl_lds16(Ab + (size_t)row * 2048 + kt * 128 + col, As + it * 4096 + wid * 1024);
      gl_lds16(Bb + (size_t)row * 2048 + kt * 128 + col, Bs + it * 4096 + wid * 1024);
    }
    __syncthreads();
    #pragma unroll
    for (int kc = 0; kc < 2; kc++) {
      bf16x8 af[4], bfr[4];
      #pragma unroll
      for (int m = 0; m < 4; m++) {
        int row = wm * 64 + m * 16 + (lane & 15);
        int e = row * 128 + kc * 64 + ((lane >> 4) << 4);
        af[m] = *(const bf16x8*)(As + (e ^ ((row & 7) << 4)));
      }
      #pragma unroll
      for (int n = 0; n < 4; n++) {
        int row = wn * 64 + n * 16 + (lane & 15);
        int e = row * 128 + kc * 64 + ((lane >> 4) << 4);
        bfr[n] = *(const bf16x8*)(Bs + (e ^ ((row & 7) << 4)));
      }
      #pragma unroll
      for (int m = 0; m < 4; m++)
        #pragma unroll
        for (int n = 0; n < 4; n++)
          acc[m][n] = __builtin_amdgcn_mfma_f32_16x16x32_bf16(af[m], bfr[n], acc[m][n], 0, 0, 0);
    }
    __syncthreads();
  }
  if (tid < 128) {
    int rl = (int)arow0 + tid - segpos;
    int t = (rl & (LR - 1)) * rate + (rl >> 11);
    drow[tid] = segpos + perm[segpos + t];
  }
  __syncthreads();
  float bv[4];
  #pragma unroll
  for (int n = 0; n < 4; n++) bv[n] = bias[nb * 128 + wn * 64 + n * 16 + (lane & 15)];
  #pragma unroll
  for (int m = 0; m < 4; m++)
    #pragma unroll
    for (int j = 0; j < 4; j++) {
      int r = wm * 64 + m * 16 + ((lane >> 4) << 2) + j;
      int gr = drow[r];
      float* orow = Out + (size_t)gr * 1024 + nb * 128 + wn * 64;
      #pragma unroll
      for (int n = 0; n < 4; n++)
        orow[n * 16 + (lane & 15)] = acc[m][n][j] + bv[n];
    }
}

// ---------------- launch ----------------
extern "C" void kernel_launch(void* const* d_in, const int* in_sizes, int n_in,
                              void* d_out, int out_size, void* d_ws, size_t ws_size,
                              hipStream_t stream) {
  (void)in_sizes; (void)n_in; (void)out_size;
  const float* x = (const float*)d_in[0];
  const float* wqkv0 = (const float*)d_in[3];
  const float* bqkv0 = (const float*)d_in[4];
  const float* wo0 = (const float*)d_in[5];
  const float* bo0 = (const float*)d_in[6];
  const float* wqkv1 = (const float*)d_in[7];
  const float* bqkv1 = (const float*)d_in[8];
  const float* wo1 = (const float*)d_in[9];
  const float* bo1 = (const float*)d_in[10];
  const float* wqkv2 = (const float*)d_in[11];
  const float* bqkv2 = (const float*)d_in[12];
  const float* wo2 = (const float*)d_in[13];
  const float* bo2 = (const float*)d_in[14];

  if (ws_size < 172032000ull) return;
  char* ws = (char*)d_ws;
  int* perm = (int*)ws;                        //     57,344 B
  u16* xh    = (u16*)(ws + 65536);             // 29,360,128 B
  u16* wqkvt = (u16*)(ws + 29425664);          // 18,874,368 B
  u16* wot   = (u16*)(ws + 48300032);          //  6,291,456 B
  u16* qkv   = (u16*)(ws + 54591488);          // 88,080,384 B
  u16* opre  = (u16*)(ws + 142671872);         // 29,360,128 B
  float* out = (float*)d_out;

  hilbert_kernel<<<56, 256, 0, stream>>>(perm);
  wtrans_kernel<<<dim3(96, 32, 3), dim3(32, 8), 0, stream>>>(wqkv0, wqkv1, wqkv2, wqkvt, 1024, 3072, 0);
  wtrans_kernel<<<dim3(32, 32, 3), dim3(32, 8), 0, stream>>>(wo0, wo1, wo2, wot, 1024, 1024, 1);
  gather_kernel<<<14336, 256, 0, stream>>>(x, perm, xh);
  qkv_gemm_kernel<<<dim3(112, 24), 256, 0, stream>>>(xh, wqkvt, bqkv0, bqkv1, bqkv2, qkv);
  attn_kernel<<<dim3(32, 48), 256, 0, stream>>>(qkv, opre);
  out_gemm_kernel<<<dim3(112, 8), 256, 0, stream>>>(opre, wot, bo0, bo1, bo2, perm, out);
}

// Round 7
// 305.733 us; speedup vs baseline: 1.3905x; 1.2380x over previous
//
#include <hip/hip_runtime.h>
#include <stdint.h>
#include <stddef.h>

typedef unsigned short u16;
typedef short bf16x8 __attribute__((ext_vector_type(8)));
typedef float f32x4 __attribute__((ext_vector_type(4)));
typedef float f32x16 __attribute__((ext_vector_type(16)));
typedef unsigned short ushort8v __attribute__((ext_vector_type(8)));
typedef int i32x2 __attribute__((ext_vector_type(2)));

#define LR 2048
#define LOG2E 1.44269504088896f

__device__ __forceinline__ u16 f2bf(float f) {
  unsigned u = __float_as_uint(f);
  unsigned r = u + 0x7fffu + ((u >> 16) & 1u);
  return (u16)(r >> 16);
}

// pack two floats -> one dword of 2 bf16 (RNE), pure C (no asm: hazard-safe)
__device__ __forceinline__ unsigned packbf(float lo, float hi) {
  return (unsigned)f2bf(lo) | ((unsigned)f2bf(hi) << 16);
}

// v_permlane32_swap: vdst[32:63] <-> vsrc[0:31]
// after plswap(a,b): a = {a_lo, b_lo}, b = {a_hi, b_hi}  (lane i <-> lane 32+i)
__device__ __forceinline__ void plswap(unsigned& a, unsigned& b) {
#if __has_builtin(__builtin_amdgcn_permlane32_swap)
  i32x2 r = __builtin_amdgcn_permlane32_swap((int)a, (int)b, false, false);
  a = (unsigned)r[0];
  b = (unsigned)r[1];
#else
  asm volatile("s_nop 1\n\tv_permlane32_swap_b32 %0, %1\n\ts_nop 1"
               : "+v"(a), "+v"(b));
#endif
}
__device__ __forceinline__ float xhalf_max(float x) {
  unsigned a = __float_as_uint(x), b = __float_as_uint(x);
  plswap(a, b);
  return fmaxf(__uint_as_float(a), __uint_as_float(b));
}
__device__ __forceinline__ float xhalf_sum(float x) {
  unsigned a = __float_as_uint(x), b = __float_as_uint(x);
  plswap(a, b);
  return __uint_as_float(a) + __uint_as_float(b);
}

__device__ __forceinline__ void gl_lds16(const void* g, void* l) {
  __builtin_amdgcn_global_load_lds((__attribute__((address_space(1))) void*)g,
                                   (__attribute__((address_space(3))) void*)l,
                                   16, 0, 0);
}

// ---------------- Hilbert permutation (closed form, no sort) ----------------
__global__ void hilbert_kernel(int* __restrict__ perm) {
  int idx = blockIdx.x * 256 + threadIdx.x;
  if (idx >= 14336) return;
  int seg = (idx < 2048) ? 0 : (idx < 6144 ? 1 : 2);
  int segpos = (seg == 0) ? 0 : (seg == 1 ? 2048 : 6144);
  int L = 2048 << seg;
  int n = (seg == 2) ? 128 : 64;
  int t = idx - segpos;
  int d = (L == n * n) ? t : ((t < (L >> 1)) ? t : t + L);
  int x = 0, y = 0;
  for (int s = 1; s < n; s <<= 1) {
    int rx = 1 & (d >> 1);
    int ry = 1 & (d ^ rx);
    if (ry == 0) {
      if (rx == 1) { x = s - 1 - x; y = s - 1 - y; }
      int tmp = x; x = y; y = tmp;
    }
    x += s * rx; y += s * ry;
    d >>= 2;
  }
  perm[idx] = y * n + x;
}

// ---------------- weight transpose + convert: [K][N] f32 -> [N][K] bf16 ------
__global__ void wtrans_kernel(const float* __restrict__ s0, const float* __restrict__ s1,
                              const float* __restrict__ s2, u16* __restrict__ dst,
                              int K, int N, int do_remap) {
  const int seg = blockIdx.z;
  const float* S = (seg == 0) ? s0 : (seg == 1 ? s1 : s2);
  u16* D = dst + (size_t)seg * K * N;
  __shared__ float tl[32][33];
  int n0 = blockIdx.x * 32, k0 = blockIdx.y * 32;
  int tx = threadIdx.x, ty = threadIdx.y;  // (32,8)
  #pragma unroll
  for (int i = 0; i < 4; i++)
    tl[ty + 8 * i][tx] = S[(size_t)(k0 + ty + 8 * i) * N + n0 + tx];
  __syncthreads();
  int kk = k0 + tx;
  if (do_remap) {
    int rate = 1 << seg;
    int h = kk >> 6;
    int h2 = (h & (rate - 1)) * (16 >> seg) + (h >> seg);
    kk = h2 * 64 + (kk & 63);
  }
  #pragma unroll
  for (int i = 0; i < 4; i++)
    D[(size_t)(n0 + ty + 8 * i) * K + kk] = f2bf(tl[tx][ty + 8 * i]);
}

// ---------------- gather x rows: hilbert perm + dilation reorder, f32->bf16 --
__global__ void gather_kernel(const float* __restrict__ x, const int* __restrict__ perm,
                              u16* __restrict__ xh) {
  int rr = blockIdx.x;
  int seg = (rr < 2048) ? 0 : (rr < 6144 ? 1 : 2);
  int segpos = (seg == 0) ? 0 : (seg == 1 ? 2048 : 6144);
  int rate = 1 << seg;
  int rl = rr - segpos;
  int t = (rl & (LR - 1)) * rate + (rl >> 11);
  int orig = segpos + perm[segpos + t];
  float4 v = *((const float4*)(x + (size_t)orig * 1024) + threadIdx.x);
  ushort4 o;
  o.x = f2bf(v.x); o.y = f2bf(v.y); o.z = f2bf(v.z); o.w = f2bf(v.w);
  *((ushort4*)(xh + (size_t)rr * 1024) + threadIdx.x) = o;
}

// ---------------- QKV GEMM: [14336,1024] x per-seg W^T[3072,1024] -> bf16 ----
__global__ __launch_bounds__(256) void qkv_gemm_kernel(
    const u16* __restrict__ A, const u16* __restrict__ Bt,
    const float* __restrict__ b0, const float* __restrict__ b1,
    const float* __restrict__ b2, u16* __restrict__ C) {
  __shared__ char smem[35328];
  char* As = smem;           // [128][64] bf16, swizzled
  char* Bs = smem + 16384;
  const int tid = threadIdx.x;
  const int lane = tid & 63, wid = tid >> 6;
  const int wm = wid >> 1, wn = wid & 1;
  const int rb = blockIdx.x, nb = blockIdx.y;
  const int seg = (rb < 16) ? 0 : (rb < 48 ? 1 : 2);
  const float* bias = (seg == 0) ? b0 : (seg == 1 ? b1 : b2);
  const size_t arow0 = (size_t)rb * 128;
  const char* Ab = (const char*)(A + arow0 * 1024);
  const char* Bb = (const char*)(Bt + ((size_t)seg * 3072 + (size_t)nb * 128) * 1024);

  f32x4 acc[4][4] = {};

  for (int kt = 0; kt < 16; kt++) {
    #pragma unroll
    for (int it = 0; it < 4; it++) {
      int p = (it * 256 + tid) * 16;
      int e = p ^ (((p >> 7) & 7) << 4);
      int row = e >> 7, col = e & 127;
      gl_lds16(Ab + (size_t)row * 2048 + kt * 128 + col, As + it * 4096 + wid * 1024);
      gl_lds16(Bb + (size_t)row * 2048 + kt * 128 + col, Bs + it * 4096 + wid * 1024);
    }
    __syncthreads();
    #pragma unroll
    for (int kc = 0; kc < 2; kc++) {
      bf16x8 af[4], bfr[4];
      #pragma unroll
      for (int m = 0; m < 4; m++) {
        int row = wm * 64 + m * 16 + (lane & 15);
        int e = row * 128 + kc * 64 + ((lane >> 4) << 4);
        af[m] = *(const bf16x8*)(As + (e ^ ((row & 7) << 4)));
      }
      #pragma unroll
      for (int n = 0; n < 4; n++) {
        int row = wn * 64 + n * 16 + (lane & 15);
        int e = row * 128 + kc * 64 + ((lane >> 4) << 4);
        bfr[n] = *(const bf16x8*)(Bs + (e ^ ((row & 7) << 4)));
      }
      #pragma unroll
      for (int m = 0; m < 4; m++)
        #pragma unroll
        for (int n = 0; n < 4; n++)
          acc[m][n] = __builtin_amdgcn_mfma_f32_16x16x32_bf16(af[m], bfr[n], acc[m][n], 0, 0, 0);
    }
    __syncthreads();
  }
  float bv[4];
  #pragma unroll
  for (int n = 0; n < 4; n++) bv[n] = bias[nb * 128 + wn * 64 + n * 16 + (lane & 15)];
  #pragma unroll
  for (int m = 0; m < 4; m++)
    #pragma unroll
    for (int n = 0; n < 4; n++)
      #pragma unroll
      for (int j = 0; j < 4; j++) {
        int r = wm * 64 + m * 16 + ((lane >> 4) << 2) + j;
        int c = wn * 64 + n * 16 + (lane & 15);
        *(u16*)(smem + r * 272 + c * 2) = f2bf(acc[m][n][j] + bv[n]);
      }
  __syncthreads();
  #pragma unroll
  for (int it = 0; it < 8; it++) {
    int ci = it * 256 + tid;
    int row = ci >> 4, c16 = ci & 15;
    bf16x8 vv = *(const bf16x8*)(smem + row * 272 + c16 * 16);
    u16* crow = C + (arow0 + row) * 3072 + nb * 128;
    *(bf16x8*)((char*)crow + c16 * 16) = vv;
  }
}

// ---------------- flash attention v4.2: swapped QK^T 32x32, in-register softmax
// cross-lane ops via builtin permlane32_swap (hazard-safe); pure-C bf16 pack
__global__ __launch_bounds__(256) void attn_kernel(const u16* __restrict__ qkv,
                                                   u16* __restrict__ opre) {
  __shared__ char smem[32768];
  // Ks dbuf at smem + cur*8192; Vt dbuf at smem + 16384 + cur*8192
  const int tid = threadIdx.x;
  const int lane = tid & 63;
  const int wid = tid >> 6;
  const int l31 = lane & 31;
  const int hi = lane >> 5;
  const int by = blockIdx.y;
  const int seg = by >> 4, h = by & 15;
  const int segrow = (seg == 0) ? 0 : (seg == 1 ? 2048 : 6144);
  const int rate = 1 << seg;
  const int off = h & (rate - 1);
  const int base = segrow + off * LR;   // head's contiguous 2048 rows
  const int h_col = off * (16 >> seg) + (h >> seg);
  const int q0 = blockIdx.x * 128;
  const int qw = q0 + wid * 32;
  const char* qb = (const char*)qkv;

  // V transpose mapping: thread owns 2 keys x 8 d
  const int vkey0 = 2 * (tid & 31);
  const int vd0 = (tid >> 5) * 8;

  // ---- prologue: stage K0 (gl_lds), V0 regs, Q B-fragments direct to regs ----
  #pragma unroll
  for (int it = 0; it < 2; it++) {
    int p = (it * 256 + tid) * 16;
    int e = p ^ (((p >> 7) & 7) << 4);
    int row = e >> 7, col = e & 127;
    gl_lds16(qb + (size_t)(base + row) * 6144 + 2048 + h * 128 + col,
             smem + it * 4096 + wid * 1024);
  }
  ushort8v v0r = *(const ushort8v*)(qb + (size_t)(base + vkey0) * 6144 + 4096 + h * 128 + vd0 * 2);
  ushort8v v1r = *(const ushort8v*)(qb + (size_t)(base + vkey0 + 1) * 6144 + 4096 + h * 128 + vd0 * 2);
  bf16x8 qf[4];
  #pragma unroll
  for (int i = 0; i < 4; i++)
    qf[i] = *(const bf16x8*)(qb + (size_t)(base + qw + l31) * 6144 + h * 128 + i * 32 + hi * 16);
  // write Vt[0]
  #pragma unroll
  for (int dd = 0; dd < 8; dd++) {
    int d = vd0 + dd;
    unsigned val = (unsigned)(u16)v0r[dd] | ((unsigned)(u16)v1r[dd] << 16);
    int addr = d * 128 + vkey0 * 2;
    *(unsigned*)(smem + 16384 + (addr ^ ((d & 7) << 4))) = val;
  }
  __syncthreads();

  float Mrun = -INFINITY, Lrun = 0.f;
  f32x16 accO0 = {}, accO1 = {};
  const float K1 = 0.125f * LOG2E;

  for (int kt = 0; kt < 32; kt++) {
    const int cur = kt & 1;
    const int nxt = cur ^ 1;
    char* Ks  = smem + (cur << 13);
    char* Vt  = smem + 16384 + (cur << 13);
    char* Ksn = smem + (nxt << 13);
    char* Vtn = smem + 16384 + (nxt << 13);
    ushort8v nv0, nv1;
    if (kt < 31) {  // issue next tile's loads early
      #pragma unroll
      for (int it = 0; it < 2; it++) {
        int p = (it * 256 + tid) * 16;
        int e = p ^ (((p >> 7) & 7) << 4);
        int row = e >> 7, col = e & 127;
        gl_lds16(qb + (size_t)(base + (kt + 1) * 64 + row) * 6144 + 2048 + h * 128 + col,
                 Ksn + it * 4096 + wid * 1024);
      }
      nv0 = *(const ushort8v*)(qb + (size_t)(base + (kt + 1) * 64 + vkey0) * 6144 + 4096 + h * 128 + vd0 * 2);
      nv1 = *(const ushort8v*)(qb + (size_t)(base + (kt + 1) * 64 + vkey0 + 1) * 6144 + 4096 + h * 128 + vd0 * 2);
    }
    #pragma unroll
    for (int s = 0; s < 2; s++) {
      // QK^T: sacc[r] = S[key = s*32 + (r&3)+8*(r>>2)+4*hi][q=l31]
      f32x16 sacc = {};
      #pragma unroll
      for (int i = 0; i < 4; i++) {
        int row = s * 32 + l31;
        int addr = (row * 128 + i * 32 + hi * 16) ^ ((row & 7) << 4);
        bf16x8 kf = *(const bf16x8*)(Ks + addr);
        sacc = __builtin_amdgcn_mfma_f32_32x32x16_bf16(kf, qf[i], sacc, 0, 0, 0);
      }
      // in-register softmax over 32 keys (16 local + cross-half swap)
      float t8[8];
      #pragma unroll
      for (int t = 0; t < 8; t++) t8[t] = fmaxf(sacc[2 * t], sacc[2 * t + 1]);
      float m01 = fmaxf(fmaxf(t8[0], t8[1]), fmaxf(t8[2], t8[3]));
      float m23 = fmaxf(fmaxf(t8[4], t8[5]), fmaxf(t8[6], t8[7]));
      float m = xhalf_max(fmaxf(m01, m23)) * 0.125f;
      if (!__all(m - Mrun <= 8.0f)) {
        float mnew = fmaxf(Mrun, m);
        float rf = exp2f((Mrun - mnew) * LOG2E);
        Lrun *= rf;
        #pragma unroll
        for (int r = 0; r < 16; r++) { accO0[r] *= rf; accO1[r] *= rf; }
        Mrun = mnew;
      }
      float c2 = Mrun * LOG2E;
      #pragma unroll
      for (int r = 0; r < 16; r++) sacc[r] = exp2f(sacc[r] * K1 - c2);
      float s8[8];
      #pragma unroll
      for (int t = 0; t < 8; t++) s8[t] = sacc[2 * t] + sacc[2 * t + 1];
      float sm = (((s8[0] + s8[1]) + (s8[2] + s8[3])) + ((s8[4] + s8[5]) + (s8[6] + s8[7])));
      Lrun += xhalf_sum(sm);
      // pack P -> two A-fragments. w[t] pre-swap on (hi=0|hi=1): key pairs
      // {(0,1),(2,3),(8,9),(10,11),(16,17),(18,19),(24,25),(26,27)} (+4*hi).
      // plswap(a,b): a={a_lo,b_lo}, b={a_hi,b_hi} =>
      //   w0={(0,1),(8,9)}, w2={(4,5),(12,13)}, w1={(2,3),(10,11)}, w3={(6,7),(14,15)}
      unsigned w[8];
      #pragma unroll
      for (int t = 0; t < 8; t++) w[t] = packbf(sacc[2 * t], sacc[2 * t + 1]);
      plswap(w[0], w[2]); plswap(w[1], w[3]);
      plswap(w[4], w[6]); plswap(w[5], w[7]);
      union PU { unsigned u[4]; bf16x8 v; };
      PU pu0, pu1;
      pu0.u[0] = w[0]; pu0.u[1] = w[1]; pu0.u[2] = w[2]; pu0.u[3] = w[3];
      pu1.u[0] = w[4]; pu1.u[1] = w[5]; pu1.u[2] = w[6]; pu1.u[3] = w[7];
      // PV: accO[dt] += P(16 keys per j) x Vt
      #pragma unroll
      for (int j = 0; j < 2; j++) {
        bf16x8 pa = (j == 0) ? pu0.v : pu1.v;
        #pragma unroll
        for (int dt = 0; dt < 2; dt++) {
          int d = dt * 32 + l31;
          int addr = (d * 128 + s * 64 + j * 32 + hi * 16) ^ ((d & 7) << 4);
          bf16x8 vf = *(const bf16x8*)(Vt + addr);
          if (dt == 0) accO0 = __builtin_amdgcn_mfma_f32_32x32x16_bf16(pa, vf, accO0, 0, 0, 0);
          else         accO1 = __builtin_amdgcn_mfma_f32_32x32x16_bf16(pa, vf, accO1, 0, 0, 0);
        }
      }
    }
    // write next V tile late
    if (kt < 31) {
      #pragma unroll
      for (int dd = 0; dd < 8; dd++) {
        int d = vd0 + dd;
        unsigned val = (unsigned)(u16)nv0[dd] | ((unsigned)(u16)nv1[dd] << 16);
        int addr = d * 128 + vkey0 * 2;
        *(unsigned*)(Vtn + (addr ^ ((d & 7) << 4))) = val;
      }
    }
    __syncthreads();
  }

  // ---- epilogue: O -> LDS (coalesce) -> global ----
  float invL = 1.0f / Lrun;
  #pragma unroll
  for (int r = 0; r < 16; r++) {
    int qrow = (r & 3) + 8 * (r >> 2) + 4 * hi;
    float li = __shfl(invL, qrow);
    int qloc = wid * 32 + qrow;
    int a0 = (qloc * 128 + l31 * 2) ^ ((qrow & 7) << 4);
    int a1 = (qloc * 128 + 64 + l31 * 2) ^ ((qrow & 7) << 4);
    *(u16*)(smem + a0) = f2bf(accO0[r] * li);
    *(u16*)(smem + a1) = f2bf(accO1[r] * li);
  }
  __syncthreads();
  #pragma unroll
  for (int it = 0; it < 4; it++) {
    int idx = it * 256 + tid;
    int row = idx >> 3, c16 = idx & 7;
    int a = (row * 128 + c16 * 16) ^ ((row & 7) << 4);
    bf16x8 vv = *(const bf16x8*)(smem + a);
    *(bf16x8*)((char*)(opre + (size_t)(base + q0 + row) * 1024 + h_col * 64) + c16 * 16) = vv;
  }
}

// ---------------- OUT GEMM: residue-sparse [14336,1024] x Wo^T -> f32 --------
__global__ __launch_bounds__(256) void out_gemm_kernel(
    const u16* __restrict__ A, const u16* __restrict__ Bt,
    const float* __restrict__ b0, const float* __restrict__ b1,
    const float* __restrict__ b2, const int* __restrict__ perm,
    float* __restrict__ Out) {
  __shared__ char smem[32768];
  __shared__ int drow[128];
  char* As = smem;
  char* Bs = smem + 16384;
  const int tid = threadIdx.x;
  const int lane = tid & 63, wid = tid >> 6;
  const int wm = wid >> 1, wn = wid & 1;
  const int rb = blockIdx.x, nb = blockIdx.y;
  const int seg = (rb < 16) ? 0 : (rb < 48 ? 1 : 2);
  const int segpos = (seg == 0) ? 0 : (seg == 1 ? 2048 : 6144);
  const int rate = 1 << seg;
  const float* bias = (seg == 0) ? b0 : (seg == 1 ? b1 : b2);
  const size_t arow0 = (size_t)rb * 128;
  const char* Ab = (const char*)(A + arow0 * 1024);
  const char* Bb = (const char*)(Bt + ((size_t)seg * 1024 + (size_t)nb * 128) * 1024);

  const int blk = (int)(arow0 - segpos) >> 11;
  const int ktpb = 16 >> seg;
  const int kt0 = blk * ktpb;

  f32x4 acc[4][4] = {};

  for (int kt = kt0; kt < kt0 + ktpb; kt++) {
    #pragma unroll
    for (int it = 0; it < 4; it++) {
      int p = (it * 256 + tid) * 16;
      int e = p ^ (((p >> 7) & 7) << 4);
      int row = e >> 7, col = e & 127;
      gl_lds16(Ab + (size_t)row * 2048 + kt * 128 + col, As + it * 4096 + wid * 1024);
      gl_lds16(Bb + (size_t)row * 2048 + kt * 128 + col, Bs + it * 4096 + wid * 1024);
    }
    __syncthreads();
    #pragma unroll
    for (int kc = 0; kc < 2; kc++) {
      bf16x8 af[4], bfr[4];
      #pragma unroll
      for (int m = 0; m < 4; m++) {
        int row = wm * 64 + m * 16 + (lane & 15);
        int e = row * 128 + kc * 64 + ((lane >> 4) << 4);
        af[m] = *(const bf16x8*)(As + (e ^ ((row & 7) << 4)));
      }
      #pragma unroll
      for (int n = 0; n < 4; n++) {
        int row = wn * 64 + n * 16 + (lane & 15);
        int e = row * 128 + kc * 64 + ((lane >> 4) << 4);
        bfr[n] = *(const bf16x8*)(Bs + (e ^ ((row & 7) << 4)));
      }
      #pragma unroll
      for (int m = 0; m < 4; m++)
        #pragma unroll
        for (int n = 0; n < 4; n++)
          acc[m][n] = __builtin_amdgcn_mfma_f32_16x16x32_bf16(af[m], bfr[n], acc[m][n], 0, 0, 0);
    }
    __syncthreads();
  }
  if (tid < 128) {
    int rl = (int)arow0 + tid - segpos;
    int t = (rl & (LR - 1)) * rate + (rl >> 11);
    drow[tid] = segpos + perm[segpos + t];
  }
  __syncthreads();
  float bv[4];
  #pragma unroll
  for (int n = 0; n < 4; n++) bv[n] = bias[nb * 128 + wn * 64 + n * 16 + (lane & 15)];
  #pragma unroll
  for (int m = 0; m < 4; m++)
    #pragma unroll
    for (int j = 0; j < 4; j++) {
      int r = wm * 64 + m * 16 + ((lane >> 4) << 2) + j;
      int gr = drow[r];
      float* orow = Out + (size_t)gr * 1024 + nb * 128 + wn * 64;
      #pragma unroll
      for (int n = 0; n < 4; n++)
        orow[n * 16 + (lane & 15)] = acc[m][n][j] + bv[n];
    }
}

// ---------------- launch ----------------
extern "C" void kernel_launch(void* const* d_in, const int* in_sizes, int n_in,
                              void* d_out, int out_size, void* d_ws, size_t ws_size,
                              hipStream_t stream) {
  (void)in_sizes; (void)n_in; (void)out_size;
  const float* x = (const float*)d_in[0];
  const float* wqkv0 = (const float*)d_in[3];
  const float* bqkv0 = (const float*)d_in[4];
  const float* wo0 = (const float*)d_in[5];
  const float* bo0 = (const float*)d_in[6];
  const float* wqkv1 = (const float*)d_in[7];
  const float* bqkv1 = (const float*)d_in[8];
  const float* wo1 = (const float*)d_in[9];
  const float* bo1 = (const float*)d_in[10];
  const float* wqkv2 = (const float*)d_in[11];
  const float* bqkv2 = (const float*)d_in[12];
  const float* wo2 = (const float*)d_in[13];
  const float* bo2 = (const float*)d_in[14];

  if (ws_size < 172032000ull) return;
  char* ws = (char*)d_ws;
  int* perm = (int*)ws;                        //     57,344 B
  u16* xh    = (u16*)(ws + 65536);             // 29,360,128 B
  u16* wqkvt = (u16*)(ws + 29425664);          // 18,874,368 B
  u16* wot   = (u16*)(ws + 48300032);          //  6,291,456 B
  u16* qkv   = (u16*)(ws + 54591488);          // 88,080,384 B
  u16* opre  = (u16*)(ws + 142671872);         // 29,360,128 B
  float* out = (float*)d_out;

  hilbert_kernel<<<56, 256, 0, stream>>>(perm);
  wtrans_kernel<<<dim3(96, 32, 3), dim3(32, 8), 0, stream>>>(wqkv0, wqkv1, wqkv2, wqkvt, 1024, 3072, 0);
  wtrans_kernel<<<dim3(32, 32, 3), dim3(32, 8), 0, stream>>>(wo0, wo1, wo2, wot, 1024, 1024, 1);
  gather_kernel<<<14336, 256, 0, stream>>>(x, perm, xh);
  qkv_gemm_kernel<<<dim3(112, 24), 256, 0, stream>>>(xh, wqkvt, bqkv0, bqkv1, bqkv2, qkv);
  attn_kernel<<<dim3(16, 48), 256, 0, stream>>>(qkv, opre);
  out_gemm_kernel<<<dim3(112, 8), 256, 0, stream>>>(opre, wot, bo0, bo1, bo2, perm, out);
}